// Round 1
// baseline (225.865 us; speedup 1.0000x reference)
//
#include <hip/hip_runtime.h>
#include <hip/hip_bf16.h>
#include <stdint.h>

// Problem constants: B=2, S=2048, D=768, H=12, DK=64
typedef __attribute__((ext_vector_type(8))) short bf16x8;
typedef __attribute__((ext_vector_type(4))) short bf16x4;
typedef __attribute__((ext_vector_type(4))) float f32x4;

__device__ __forceinline__ unsigned short f2bf(float x) {
  union { __hip_bfloat16 h; unsigned short s; } u;
  u.h = __float2bfloat16(x);
  return u.s;
}

// ---------------- mask pack: int32 [B,1,S,S] -> bit per key ----------------
__global__ __launch_bounds__(256) void maskpack_kernel(const int* __restrict__ mask,
                                                       unsigned int* __restrict__ mp,
                                                       int total) {
  int i = blockIdx.x * blockDim.x + threadIdx.x;
  const int lane = threadIdx.x & 63;
  const int stride = gridDim.x * blockDim.x;
  for (; i < total; i += stride) {
    unsigned long long b = __ballot(mask[i] != 0);
    if (lane == 0)       mp[i >> 5] = (unsigned int)b;
    else if (lane == 32) mp[i >> 5] = (unsigned int)(b >> 32);
  }
}

// ---------------- projection GEMM: y = X @ W^T, epilogue -> [B,H,S,64] bf16 ----------------
// X fp32 [4096,768], W fp32 [768,768] (row n = output feature), out bf16 head-layout.
// q (z==0) is pre-scaled by 1/8 = 1/sqrt(DK).
__global__ __launch_bounds__(256) void proj_gemm(
    const float* __restrict__ Qi, const float* __restrict__ Ki, const float* __restrict__ Vi,
    const float* __restrict__ Wq, const float* __restrict__ Wk, const float* __restrict__ Wv,
    unsigned short* __restrict__ qo, unsigned short* __restrict__ ko, unsigned short* __restrict__ vo) {
  constexpr int LDT = 56;  // padded LDS row stride (112B, 16B-aligned, 2-way-max banks)
  __shared__ unsigned short As[128][LDT];
  __shared__ unsigned short Bs[128][LDT];
  const int z = blockIdx.z;
  const float* A = (z == 0) ? Qi : (z == 1) ? Ki : Vi;
  const float* W = (z == 0) ? Wq : (z == 1) ? Wk : Wv;
  unsigned short* O = (z == 0) ? qo : (z == 1) ? ko : vo;
  const float scale = (z == 0) ? 0.125f : 1.0f;
  const int m0 = blockIdx.y * 128, n0 = blockIdx.x * 128;
  const int t = threadIdx.x, lane = t & 63, w = t >> 6;
  const int wr = w >> 1, wc = w & 1;
  const int fr = lane & 15, fg = (lane >> 4) * 8;
  const int srow = t >> 3, sseg = t & 7;
  f32x4 acc[4][4] = {};
  for (int kk = 0; kk < 768; kk += 32) {
    for (int pp = 0; pp < 4; ++pp) {
      int row = srow + pp * 32;
      float4 fa = *(const float4*)&A[(size_t)(m0 + row) * 768 + kk + sseg * 4];
      float4 fb = *(const float4*)&W[(size_t)(n0 + row) * 768 + kk + sseg * 4];
      bf16x4 pa = {(short)f2bf(fa.x), (short)f2bf(fa.y), (short)f2bf(fa.z), (short)f2bf(fa.w)};
      bf16x4 pb = {(short)f2bf(fb.x), (short)f2bf(fb.y), (short)f2bf(fb.z), (short)f2bf(fb.w)};
      *(bf16x4*)&As[row][sseg * 4] = pa;
      *(bf16x4*)&Bs[row][sseg * 4] = pb;
    }
    __syncthreads();
    bf16x8 af[4], bfr[4];
    for (int i = 0; i < 4; ++i) af[i]  = *(const bf16x8*)&As[wr * 64 + i * 16 + fr][fg];
    for (int i = 0; i < 4; ++i) bfr[i] = *(const bf16x8*)&Bs[wc * 64 + i * 16 + fr][fg];
    for (int i = 0; i < 4; ++i)
      for (int j = 0; j < 4; ++j)
        acc[i][j] = __builtin_amdgcn_mfma_f32_16x16x32_bf16(af[i], bfr[j], acc[i][j], 0, 0, 0);
    __syncthreads();
  }
  // C/D layout: col = lane&15, row = (lane>>4)*4 + r  [m89]
  for (int i = 0; i < 4; ++i)
    for (int j = 0; j < 4; ++j)
      for (int r = 0; r < 4; ++r) {
        int m = m0 + wr * 64 + i * 16 + (lane >> 4) * 4 + r;
        int n = n0 + wc * 64 + j * 16 + fr;
        int b = m >> 11, s = m & 2047, h = n >> 6, dk = n & 63;
        O[((size_t)(b * 12 + h) * 2048 + s) * 64 + dk] = f2bf(acc[i][j][r] * scale);
      }
}

// ---------------- output GEMM: out = attn(bf16) @ W_O^T -> fp32 ----------------
__global__ __launch_bounds__(256) void out_gemm(
    const unsigned short* __restrict__ Ain, const float* __restrict__ W,
    float* __restrict__ Out) {
  constexpr int LDT = 56;
  __shared__ unsigned short As[128][LDT];
  __shared__ unsigned short Bs[128][LDT];
  const int m0 = blockIdx.y * 128, n0 = blockIdx.x * 128;
  const int t = threadIdx.x, lane = t & 63, w = t >> 6;
  const int wr = w >> 1, wc = w & 1;
  const int fr = lane & 15, fg = (lane >> 4) * 8;
  f32x4 acc[4][4] = {};
  for (int kk = 0; kk < 768; kk += 32) {
    {
      int row = t >> 2, seg = t & 3;
      for (int pp = 0; pp < 2; ++pp) {
        bf16x8 va = *(const bf16x8*)&Ain[(size_t)(m0 + row + pp * 64) * 768 + kk + seg * 8];
        *(bf16x8*)&As[row + pp * 64][seg * 8] = va;
      }
      int row2 = t >> 3, seg2 = t & 7;
      for (int pp = 0; pp < 4; ++pp) {
        float4 fb = *(const float4*)&W[(size_t)(n0 + row2 + pp * 32) * 768 + kk + seg2 * 4];
        bf16x4 pb = {(short)f2bf(fb.x), (short)f2bf(fb.y), (short)f2bf(fb.z), (short)f2bf(fb.w)};
        *(bf16x4*)&Bs[row2 + pp * 32][seg2 * 4] = pb;
      }
    }
    __syncthreads();
    bf16x8 af[4], bfr[4];
    for (int i = 0; i < 4; ++i) af[i]  = *(const bf16x8*)&As[wr * 64 + i * 16 + fr][fg];
    for (int i = 0; i < 4; ++i) bfr[i] = *(const bf16x8*)&Bs[wc * 64 + i * 16 + fr][fg];
    for (int i = 0; i < 4; ++i)
      for (int j = 0; j < 4; ++j)
        acc[i][j] = __builtin_amdgcn_mfma_f32_16x16x32_bf16(af[i], bfr[j], acc[i][j], 0, 0, 0);
    __syncthreads();
  }
  for (int i = 0; i < 4; ++i)
    for (int j = 0; j < 4; ++j)
      for (int r = 0; r < 4; ++r) {
        int m = m0 + wr * 64 + i * 16 + (lane >> 4) * 4 + r;
        int n = n0 + wc * 64 + j * 16 + fr;
        Out[(size_t)m * 768 + n] = acc[i][j][r];
      }
}

// ---------------- flash attention ----------------
// q,k,v bf16 [B*H, S, 64] (q pre-scaled by 1/8). 4 waves/block: 64 q-rows, 16/wave.
// K tile row-major [64][72]; V tile transposed [d][key] [64][72]; P per-wave [16][72].
__global__ __launch_bounds__(256) void attn_kernel(
    const unsigned short* __restrict__ qh, const unsigned short* __restrict__ kh,
    const unsigned short* __restrict__ vh, const unsigned int* __restrict__ mp,
    unsigned short* __restrict__ ao) {
  __shared__ unsigned short Kl[64][72];
  __shared__ unsigned short Vt[64][72];
  __shared__ unsigned short Pl[4][16][72];
  const int t = threadIdx.x, lane = t & 63, w = t >> 6;
  const int bh = blockIdx.y;
  const int bb = bh / 12, hh = bh % 12;
  const int q0 = blockIdx.x * 64 + w * 16;
  const int fr = lane & 15, fgrp = lane >> 4, fg = fgrp * 8;
  // hoisted Q fragments: row = q0+fr, k-dims fg..fg+7 (+32)
  const unsigned short* qrow = qh + ((size_t)bh * 2048 + q0 + fr) * 64;
  bf16x8 aq0 = *(const bf16x8*)(qrow + fg);
  bf16x8 aq1 = *(const bf16x8*)(qrow + 32 + fg);
  f32x4 acc[4] = {};
  float mrow[4] = {-1e30f, -1e30f, -1e30f, -1e30f};
  float lrow[4] = {0.f, 0.f, 0.f, 0.f};
  const int srow = t >> 3, sseg = t & 7;
  const unsigned short* kbase = kh + ((size_t)bh * 2048 + srow) * 64 + sseg * 8;
  const unsigned short* vbase = vh + ((size_t)bh * 2048 + srow) * 64 + sseg * 8;
  const int r0 = q0 + fgrp * 4;
  const unsigned int* mpb = mp + ((size_t)bb * 2048 + r0) * 64;

  for (int kt = 0; kt < 2048; kt += 64) {
    // ---- stage K (row-major) and V (transposed) ----
    for (int pp = 0; pp < 2; ++pp) {
      int row = srow + pp * 32;
      bf16x8 kv = *(const bf16x8*)(kbase + ((size_t)kt + pp * 32) * 64);
      bf16x8 vv = *(const bf16x8*)(vbase + ((size_t)kt + pp * 32) * 64);
      *(bf16x8*)&Kl[row][sseg * 8] = kv;
      for (int j = 0; j < 8; ++j) Vt[sseg * 8 + j][row] = (unsigned short)vv[j];
    }
    __syncthreads();
    // ---- S = q @ K^T (pre-scaled) ----
    f32x4 sc[4] = {};
    for (int ct = 0; ct < 4; ++ct) {
      bf16x8 bk0 = *(const bf16x8*)&Kl[ct * 16 + fr][fg];
      bf16x8 bk1 = *(const bf16x8*)&Kl[ct * 16 + fr][32 + fg];
      sc[ct] = __builtin_amdgcn_mfma_f32_16x16x32_bf16(aq0, bk0, sc[ct], 0, 0, 0);
      sc[ct] = __builtin_amdgcn_mfma_f32_16x16x32_bf16(aq1, bk1, sc[ct], 0, 0, 0);
    }
    // ---- mask bits for this 64-key tile, one u64 per owned q-row ----
    unsigned long long mw[4];
    for (int r = 0; r < 4; ++r)
      mw[r] = *(const unsigned long long*)(mpb + (size_t)r * 64 + (kt >> 5));
    // ---- online softmax (masked p; all-masked rows stay l=0) ----
    float rmax[4];
    for (int r = 0; r < 4; ++r) {
      float v = -1e30f;
      for (int ct = 0; ct < 4; ++ct) {
        bool bit = (mw[r] >> (ct * 16 + fr)) & 1ULL;
        v = fmaxf(v, bit ? sc[ct][r] : -1e30f);
      }
      rmax[r] = v;
    }
    for (int off = 1; off < 16; off <<= 1)
      for (int r = 0; r < 4; ++r)
        rmax[r] = fmaxf(rmax[r], __shfl_xor(rmax[r], off, 64));
    float mnew[4], scl[4];
    for (int r = 0; r < 4; ++r) {
      mnew[r] = fmaxf(mrow[r], rmax[r]);
      scl[r] = __expf(mrow[r] - mnew[r]);
      mrow[r] = mnew[r];
    }
    float pv[4][4];
    float rsum[4] = {0.f, 0.f, 0.f, 0.f};
    for (int ct = 0; ct < 4; ++ct)
      for (int r = 0; r < 4; ++r) {
        bool bit = (mw[r] >> (ct * 16 + fr)) & 1ULL;
        float p = bit ? __expf(sc[ct][r] - mnew[r]) : 0.f;
        pv[ct][r] = p;
        rsum[r] += p;
      }
    for (int off = 1; off < 16; off <<= 1)
      for (int r = 0; r < 4; ++r)
        rsum[r] += __shfl_xor(rsum[r], off, 64);
    for (int r = 0; r < 4; ++r) lrow[r] = lrow[r] * scl[r] + rsum[r];
    for (int dt = 0; dt < 4; ++dt)
      for (int r = 0; r < 4; ++r) acc[dt][r] *= scl[r];
    // ---- P -> LDS (D-layout -> A-layout transpose via LDS) ----
    for (int ct = 0; ct < 4; ++ct)
      for (int r = 0; r < 4; ++r)
        Pl[w][fgrp * 4 + r][ct * 16 + fr] = f2bf(pv[ct][r]);
    // ---- O += P @ V ----
    for (int ks = 0; ks < 2; ++ks) {
      bf16x8 pa = *(const bf16x8*)&Pl[w][fr][ks * 32 + fg];
      for (int dt = 0; dt < 4; ++dt) {
        bf16x8 bv = *(const bf16x8*)&Vt[dt * 16 + fr][ks * 32 + fg];
        acc[dt] = __builtin_amdgcn_mfma_f32_16x16x32_bf16(pa, bv, acc[dt], 0, 0, 0);
      }
    }
    __syncthreads();
  }
  // ---- epilogue: normalize, store bf16 [B,S,D] ----
  for (int r = 0; r < 4; ++r) {
    float inv = (lrow[r] > 0.f) ? 1.0f / lrow[r] : 0.f;
    int row = q0 + fgrp * 4 + r;
    for (int dt = 0; dt < 4; ++dt) {
      int col = hh * 64 + dt * 16 + fr;
      ao[((size_t)bb * 2048 + row) * 768 + col] = f2bf(acc[dt][r] * inv);
    }
  }
}

extern "C" void kernel_launch(void* const* d_in, const int* in_sizes, int n_in,
                              void* d_out, int out_size, void* d_ws, size_t ws_size,
                              hipStream_t stream) {
  const float* Q  = (const float*)d_in[0];
  const float* K  = (const float*)d_in[1];
  const float* V  = (const float*)d_in[2];
  const int*   mask = (const int*)d_in[3];
  const float* WQ = (const float*)d_in[4];
  const float* WK = (const float*)d_in[5];
  const float* WV = (const float*)d_in[6];
  const float* WO = (const float*)d_in[7];
  float* out = (float*)d_out;

  char* ws = (char*)d_ws;
  // bf16 [B*H, S, 64] = 3,145,728 elems = 6,291,456 B each
  unsigned short* qh = (unsigned short*)(ws + 0);
  unsigned short* kh = (unsigned short*)(ws + 6291456);
  unsigned short* vh = (unsigned short*)(ws + 12582912);
  unsigned short* ao = (unsigned short*)(ws + 18874368);   // bf16 [B,S,D]
  unsigned int*   mp = (unsigned int*)(ws + 25165824);     // 262144 words

  maskpack_kernel<<<dim3(2048), 256, 0, stream>>>(mask, mp, 2 * 2048 * 2048);
  proj_gemm<<<dim3(6, 32, 3), 256, 0, stream>>>(Q, K, V, WQ, WK, WV, qh, kh, vh);
  attn_kernel<<<dim3(32, 24), 256, 0, stream>>>(qh, kh, vh, mp, ao);
  out_gemm<<<dim3(6, 32), 256, 0, stream>>>(ao, WO, out);
}

// Round 2
// 175.632 us; speedup vs baseline: 1.2860x; 1.2860x over previous
//
#include <hip/hip_runtime.h>
#include <hip/hip_bf16.h>
#include <stdint.h>

// Problem constants: B=2, S=2048, D=768, H=12, DK=64
typedef __attribute__((ext_vector_type(8))) short bf16x8;
typedef __attribute__((ext_vector_type(4))) short bf16x4;
typedef __attribute__((ext_vector_type(4))) float f32x4;
typedef __attribute__((ext_vector_type(16))) float f32x16;
typedef __attribute__((ext_vector_type(4))) unsigned short u16x4;

__device__ __forceinline__ unsigned short f2bf(float x) {
  union { __hip_bfloat16 h; unsigned short s; } u;
  u.h = __float2bfloat16(x);
  return u.s;
}
__device__ __forceinline__ unsigned int cvtpk(float lo, float hi) {
  unsigned int r;
  asm("v_cvt_pk_bf16_f32 %0, %1, %2" : "=v"(r) : "v"(lo), "v"(hi));
  return r;
}

// ---------------- mask pack: int32 [B,1,S,S] -> bit per key ----------------
__global__ __launch_bounds__(256) void maskpack_kernel(const int* __restrict__ mask,
                                                       unsigned int* __restrict__ mp,
                                                       int total) {
  int i = blockIdx.x * blockDim.x + threadIdx.x;
  const int lane = threadIdx.x & 63;
  const int stride = gridDim.x * blockDim.x;
  for (; i < total; i += stride) {
    unsigned long long b = __ballot(mask[i] != 0);
    if (lane == 0)       mp[i >> 5] = (unsigned int)b;
    else if (lane == 32) mp[i >> 5] = (unsigned int)(b >> 32);
  }
}

// ---------------- projection GEMM: y = X @ W^T ----------------
// q (z==0): scaled by log2(e)/8, layout [B,H,S,64].
// k (z==1): layout [B,H,S,64].  v (z==2): TRANSPOSED layout [B,H,64,S].
__global__ __launch_bounds__(256) void proj_gemm(
    const float* __restrict__ Qi, const float* __restrict__ Ki, const float* __restrict__ Vi,
    const float* __restrict__ Wq, const float* __restrict__ Wk, const float* __restrict__ Wv,
    unsigned short* __restrict__ qo, unsigned short* __restrict__ ko, unsigned short* __restrict__ vo) {
  constexpr int LDT = 56;
  __shared__ unsigned short As[128][LDT];
  __shared__ unsigned short Bs[128][LDT];
  const int z = blockIdx.z;
  const float* A = (z == 0) ? Qi : (z == 1) ? Ki : Vi;
  const float* W = (z == 0) ? Wq : (z == 1) ? Wk : Wv;
  const int m0 = blockIdx.y * 128, n0 = blockIdx.x * 128;
  const int t = threadIdx.x, lane = t & 63, w = t >> 6;
  const int wr = w >> 1, wc = w & 1;
  const int fr = lane & 15, fg = (lane >> 4) * 8;
  const int srow = t >> 3, sseg = t & 7;
  f32x4 acc[4][4] = {};
  for (int kk = 0; kk < 768; kk += 32) {
    for (int pp = 0; pp < 4; ++pp) {
      int row = srow + pp * 32;
      float4 fa = *(const float4*)&A[(size_t)(m0 + row) * 768 + kk + sseg * 4];
      float4 fb = *(const float4*)&W[(size_t)(n0 + row) * 768 + kk + sseg * 4];
      bf16x4 pa = {(short)f2bf(fa.x), (short)f2bf(fa.y), (short)f2bf(fa.z), (short)f2bf(fa.w)};
      bf16x4 pb = {(short)f2bf(fb.x), (short)f2bf(fb.y), (short)f2bf(fb.z), (short)f2bf(fb.w)};
      *(bf16x4*)&As[row][sseg * 4] = pa;
      *(bf16x4*)&Bs[row][sseg * 4] = pb;
    }
    __syncthreads();
    bf16x8 af[4], bfr[4];
    for (int i = 0; i < 4; ++i) af[i]  = *(const bf16x8*)&As[wr * 64 + i * 16 + fr][fg];
    for (int i = 0; i < 4; ++i) bfr[i] = *(const bf16x8*)&Bs[wc * 64 + i * 16 + fr][fg];
    for (int i = 0; i < 4; ++i)
      for (int j = 0; j < 4; ++j)
        acc[i][j] = __builtin_amdgcn_mfma_f32_16x16x32_bf16(af[i], bfr[j], acc[i][j], 0, 0, 0);
    __syncthreads();
  }
  if (z == 2) {
    // V^T: out[(b*12+h)*64 + dk][s], pack 4 along s (r-direction)
    for (int i = 0; i < 4; ++i)
      for (int j = 0; j < 4; ++j) {
        int m = m0 + wr * 64 + i * 16 + (lane >> 4) * 4;
        int n = n0 + wc * 64 + j * 16 + fr;
        int b = m >> 11, s = m & 2047, hd = n >> 6, dk = n & 63;
        u16x4 pk;
        for (int r = 0; r < 4; ++r) pk[r] = f2bf(acc[i][j][r]);
        *(u16x4*)&vo[((size_t)(b * 12 + hd) * 64 + dk) * 2048 + s] = pk;
      }
  } else {
    unsigned short* O = (z == 0) ? qo : ko;
    const float scale = (z == 0) ? 0.18033688f : 1.0f;  // log2(e)/8 for q
    for (int i = 0; i < 4; ++i)
      for (int j = 0; j < 4; ++j)
        for (int r = 0; r < 4; ++r) {
          int m = m0 + wr * 64 + i * 16 + (lane >> 4) * 4 + r;
          int n = n0 + wc * 64 + j * 16 + fr;
          int b = m >> 11, s = m & 2047, hd = n >> 6, dk = n & 63;
          O[((size_t)(b * 12 + hd) * 2048 + s) * 64 + dk] = f2bf(acc[i][j][r] * scale);
        }
  }
}

// ---------------- output GEMM: out = attn(bf16) @ W_O^T -> fp32 ----------------
__global__ __launch_bounds__(256) void out_gemm(
    const unsigned short* __restrict__ Ain, const float* __restrict__ W,
    float* __restrict__ Out) {
  constexpr int LDT = 56;
  __shared__ unsigned short As[128][LDT];
  __shared__ unsigned short Bs[128][LDT];
  const int m0 = blockIdx.y * 128, n0 = blockIdx.x * 128;
  const int t = threadIdx.x, lane = t & 63, w = t >> 6;
  const int wr = w >> 1, wc = w & 1;
  const int fr = lane & 15, fg = (lane >> 4) * 8;
  f32x4 acc[4][4] = {};
  for (int kk = 0; kk < 768; kk += 32) {
    {
      int row = t >> 2, seg = t & 3;
      for (int pp = 0; pp < 2; ++pp) {
        bf16x8 va = *(const bf16x8*)&Ain[(size_t)(m0 + row + pp * 64) * 768 + kk + seg * 8];
        *(bf16x8*)&As[row + pp * 64][seg * 8] = va;
      }
      int row2 = t >> 3, seg2 = t & 7;
      for (int pp = 0; pp < 4; ++pp) {
        float4 fb = *(const float4*)&W[(size_t)(n0 + row2 + pp * 32) * 768 + kk + seg2 * 4];
        bf16x4 pb = {(short)f2bf(fb.x), (short)f2bf(fb.y), (short)f2bf(fb.z), (short)f2bf(fb.w)};
        *(bf16x4*)&Bs[row2 + pp * 32][seg2 * 4] = pb;
      }
    }
    __syncthreads();
    bf16x8 af[4], bfr[4];
    for (int i = 0; i < 4; ++i) af[i]  = *(const bf16x8*)&As[wr * 64 + i * 16 + fr][fg];
    for (int i = 0; i < 4; ++i) bfr[i] = *(const bf16x8*)&Bs[wc * 64 + i * 16 + fr][fg];
    for (int i = 0; i < 4; ++i)
      for (int j = 0; j < 4; ++j)
        acc[i][j] = __builtin_amdgcn_mfma_f32_16x16x32_bf16(af[i], bfr[j], acc[i][j], 0, 0, 0);
    __syncthreads();
  }
  for (int i = 0; i < 4; ++i)
    for (int j = 0; j < 4; ++j)
      for (int r = 0; r < 4; ++r) {
        int m = m0 + wr * 64 + i * 16 + (lane >> 4) * 4 + r;
        int n = n0 + wc * 64 + j * 16 + fr;
        Out[(size_t)m * 768 + n] = acc[i][j][r];
      }
}

// ---------------- flash attention, swapped operands, 32x32x16 MFMA ----------------
// 2 waves/block, 32 q per wave. Computes S^T = K·Q^T and O^T = V^T·P^T.
// Lane owns q-column q0+(lane&31); softmax stats are lane-local scalars.
// K/V tiles in LDS, XOR-swizzled 16B chunks; 2-deep double buffer, 1 barrier/tile.
#define PVSTEP(P, OFF, A0, A1) { \
  unsigned int a0 = cvtpk(P[OFF + 0], P[OFF + 1]), a1 = cvtpk(P[OFF + 2], P[OFF + 3]); \
  unsigned int b0 = cvtpk(P[OFF + 4], P[OFF + 5]), b1 = cvtpk(P[OFF + 6], P[OFF + 7]); \
  int s0 = h ? (int)a0 : (int)b0, s1 = h ? (int)a1 : (int)b1; \
  unsigned int r0 = (unsigned int)__shfl_xor(s0, 32, 64); \
  unsigned int r1 = (unsigned int)__shfl_xor(s1, 32, 64); \
  union { unsigned int u[4]; bf16x8 v; } bfu; \
  bfu.u[0] = h ? r0 : a0; bfu.u[1] = h ? r1 : a1; \
  bfu.u[2] = h ? b0 : r0; bfu.u[3] = h ? b1 : r1; \
  acc0 = __builtin_amdgcn_mfma_f32_32x32x16_bf16(A0, bfu.v, acc0, 0, 0, 0); \
  acc1 = __builtin_amdgcn_mfma_f32_32x32x16_bf16(A1, bfu.v, acc1, 0, 0, 0); }

__global__ __launch_bounds__(128) void attn_kernel(
    const unsigned short* __restrict__ qh, const unsigned short* __restrict__ kh,
    const unsigned short* __restrict__ vh, const unsigned int* __restrict__ mp,
    unsigned short* __restrict__ ao) {
  __shared__ unsigned short Kl[2][64][64];
  __shared__ unsigned short Vl[2][64][64];
  const int t = threadIdx.x, lane = t & 63, w = t >> 6;
  const int bh = blockIdx.y, bb = bh / 12, hh = bh % 12;
  const int q0 = blockIdx.x * 64 + w * 32;
  const int qc = lane & 31, h = lane >> 5;
  const int q = q0 + qc;
  // Q B-fragments (pre-scaled by log2e/8): B[k][q], k = kc*16 + h*8 + j
  const unsigned short* qrow = qh + ((size_t)bh * 2048 + q) * 64;
  bf16x8 bq[4];
#pragma unroll
  for (int kc = 0; kc < 4; ++kc) bq[kc] = *(const bf16x8*)(qrow + kc * 16 + h * 8);
  const unsigned int* mrow = mp + ((size_t)bb * 2048 + q) * 64;
  const unsigned short* kgb = kh + (size_t)bh * 2048 * 64;
  const unsigned short* vgb = vh + (size_t)bh * 64 * 2048;  // V^T: [64][2048]
  f32x16 acc0 = {}, acc1 = {};
  float m_run = -1e30f, l_run = 0.f;
  bf16x8 stK[4], stV[4];
  auto LOADT = [&](int KT) {
#pragma unroll
    for (int i = 0; i < 4; ++i) {
      const int g = t + 128 * i, row = g >> 3, cc = g & 7;
      stK[i] = *(const bf16x8*)(kgb + (size_t)(KT + row) * 64 + cc * 8);
      stV[i] = *(const bf16x8*)(vgb + (size_t)row * 2048 + KT + cc * 8);
    }
  };
  auto STORET = [&](int BUF) {
#pragma unroll
    for (int i = 0; i < 4; ++i) {
      const int g = t + 128 * i, row = g >> 3, cc = (g & 7) ^ (row & 7);
      *(bf16x8*)&Kl[BUF][row][cc * 8] = stK[i];
      *(bf16x8*)&Vl[BUF][row][cc * 8] = stV[i];
    }
  };
  LOADT(0);
  STORET(0);
  __syncthreads();
#pragma unroll 2
  for (int it = 0; it < 32; ++it) {
    const int kt = it * 64, cur = it & 1;
    const bool more = it < 31;
    if (more) LOADT(kt + 64);  // T14: issue loads early, held in regs
    unsigned long long msh = (*(const unsigned long long*)(mrow + (kt >> 5))) >> (4 * h);
    // K A-frags: A[m=key][k], rows kb*32+qc, chunk (kc*2+h)^(qc&7)
    bf16x8 ka0[4], ka1[4];
#pragma unroll
    for (int kc = 0; kc < 4; ++kc) {
      ka0[kc] = *(const bf16x8*)&Kl[cur][qc][((kc * 2 + h) ^ (qc & 7)) * 8];
      ka1[kc] = *(const bf16x8*)&Kl[cur][32 + qc][((kc * 2 + h) ^ (qc & 7)) * 8];
    }
    f32x16 sc0 = {}, sc1 = {};
#pragma unroll
    for (int kc = 0; kc < 4; ++kc) {
      sc0 = __builtin_amdgcn_mfma_f32_32x32x16_bf16(ka0[kc], bq[kc], sc0, 0, 0, 0);
      sc1 = __builtin_amdgcn_mfma_f32_32x32x16_bf16(ka1[kc], bq[kc], sc1, 0, 0, 0);
    }
    // V A-frags (issue ds_reads; latency hidden under softmax VALU)
    bf16x8 va0[4], va1[4];
#pragma unroll
    for (int kf = 0; kf < 4; ++kf) {
      va0[kf] = *(const bf16x8*)&Vl[cur][qc][((kf * 2 + h) ^ (qc & 7)) * 8];
      va1[kf] = *(const bf16x8*)&Vl[cur][32 + qc][((kf * 2 + h) ^ (qc & 7)) * 8];
    }
    // mask (set to -3e38 so exp2 underflows to exact 0) + tile max
    float tmax = -3.0e38f;
#pragma unroll
    for (int r = 0; r < 16; ++r) {
      const int sh = (r & 3) + 8 * (r >> 2);
      if (!((msh >> sh) & 1ULL))        sc0[r] = -3.0e38f;
      if (!((msh >> (32 + sh)) & 1ULL)) sc1[r] = -3.0e38f;
      tmax = fmaxf(tmax, fmaxf(sc0[r], sc1[r]));
    }
    tmax = fmaxf(tmax, __shfl_xor(tmax, 32, 64));
    const float mnew = fmaxf(m_run, tmax);
    const float scl = exp2f(m_run - mnew);
    m_run = mnew;
    float tsum = 0.f;
#pragma unroll
    for (int r = 0; r < 16; ++r) {
      float p0 = exp2f(sc0[r] - mnew);
      float p1 = exp2f(sc1[r] - mnew);
      sc0[r] = p0; sc1[r] = p1;
      tsum += p0 + p1;
    }
    tsum += __shfl_xor(tsum, 32, 64);
    l_run = l_run * scl + tsum;
#pragma unroll
    for (int e = 0; e < 16; ++e) { acc0[e] *= scl; acc1[e] *= scl; }
    // PV: O^T += V^T · P^T  (P redistributed in-register via cvt_pk + shfl_xor32)
    PVSTEP(sc0, 0, va0[0], va1[0]);
    PVSTEP(sc0, 8, va0[1], va1[1]);
    PVSTEP(sc1, 0, va0[2], va1[2]);
    PVSTEP(sc1, 8, va0[3], va1[3]);
    if (more) STORET(1 - cur);
    __syncthreads();
  }
  // epilogue: O^T lane holds d = dt*32 + 8*rr + 4h + j for q-col q
  const float inv = (l_run > 0.f) ? 1.0f / l_run : 0.f;
  unsigned short* orow = ao + ((size_t)bb * 2048 + q) * 768 + hh * 64;
#pragma unroll
  for (int rr = 0; rr < 4; ++rr) {
    u16x4 o0, o1;
#pragma unroll
    for (int j = 0; j < 4; ++j) {
      o0[j] = f2bf(acc0[rr * 4 + j] * inv);
      o1[j] = f2bf(acc1[rr * 4 + j] * inv);
    }
    const int d0 = 8 * rr + 4 * h;
    *(u16x4*)&orow[d0] = o0;
    *(u16x4*)&orow[32 + d0] = o1;
  }
}

extern "C" void kernel_launch(void* const* d_in, const int* in_sizes, int n_in,
                              void* d_out, int out_size, void* d_ws, size_t ws_size,
                              hipStream_t stream) {
  const float* Q  = (const float*)d_in[0];
  const float* K  = (const float*)d_in[1];
  const float* V  = (const float*)d_in[2];
  const int*   mask = (const int*)d_in[3];
  const float* WQ = (const float*)d_in[4];
  const float* WK = (const float*)d_in[5];
  const float* WV = (const float*)d_in[6];
  const float* WO = (const float*)d_in[7];
  float* out = (float*)d_out;

  char* ws = (char*)d_ws;
  unsigned short* qh = (unsigned short*)(ws + 0);          // [B,H,S,64] bf16 (pre-scaled)
  unsigned short* kh = (unsigned short*)(ws + 6291456);    // [B,H,S,64] bf16
  unsigned short* vh = (unsigned short*)(ws + 12582912);   // [B,H,64,S] bf16 (transposed)
  unsigned short* ao = (unsigned short*)(ws + 18874368);   // [B,S,D] bf16
  unsigned int*   mp = (unsigned int*)(ws + 25165824);     // bitmask

  maskpack_kernel<<<dim3(2048), 256, 0, stream>>>(mask, mp, 2 * 2048 * 2048);
  proj_gemm<<<dim3(6, 32, 3), 256, 0, stream>>>(Q, K, V, WQ, WK, WV, qh, kh, vh);
  attn_kernel<<<dim3(32, 24), 128, 0, stream>>>(qh, kh, vh, mp, ao);
  out_gemm<<<dim3(6, 32), 256, 0, stream>>>(ao, WO, out);
}